// Round 4
// baseline (111.865 us; speedup 1.0000x reference)
//
#include <hip/hip_runtime.h>
#include <hip/hip_bf16.h>

// MMD loss via bf16 MFMA Gram matrix — barrier-free LDS-free GEMM core.
// R4: 128x64 per-wave tiles (8 A-frags x 4 B-frags = 32 MFMA/chunk from 12KB
// instead of 16 MFMA from 8KB): -25% L2 fragment traffic and -25% load
// instructions per MFMA, reuse held in registers (R3 proved L1 timing tricks
// don't recover duplicate fetches; barrier alignment cost +3.4us -> reverted).
// Block = 2 waves covering one 128x128 supertile -> panel decode unchanged.
// Non-persistent grid 2080 (4 blocks/CU resident = 2.03 natural rounds, no
// tail rag; cross-block overlap hides prologues).
//
// Zc layout (R7): Zc[ck][row][32], stored quad = q ^ ((row>>1)&3); each mfma
// fragment = one contiguous coalesced 1KB block.
// Lessons: R4 no __threadfence; R5 no forced occupancy past spill; R6 no
// scattered vector loads; R3/R7 barrier-drain plateau; R3(this session) no
// chunk-level s_barrier alignment.
//
// z = [xf; yf] (8192 x 256). result = (1/4096^2)*(8192*NSIG + sum_{i<j} 2 s_i s_j K_ij)
// ws: [0,4MiB) bf16 Zc; float norms[8192]; float partials[2080].

#define NSIG 5
#define CKS   262144                 // chunk stride in ushorts: 8192 rows * 32
#define NBLK2 2080                   // 64-supergrid triangle: 64*65/2

typedef __attribute__((ext_vector_type(8))) short short8;
typedef __attribute__((ext_vector_type(4))) float floatx4;

// ---- prep: (B,C,H,W) fp32 -> Zc chunked-swizzled bf16 + norms (unchanged) ----
__global__ __launch_bounds__(256) void prep_kernel(const float* __restrict__ x,
                                                   const float* __restrict__ y,
                                                   ushort* __restrict__ Zc,
                                                   float* __restrict__ norms) {
    const int bid = blockIdx.x;           // s(1) | b(2) | strip(6)
    const int t = threadIdx.x;
    const int s = bid >> 8;
    const int b = (bid >> 6) & 3;
    const int p0 = (bid & 63) << 4;
    const float* src = s ? y : x;
    const int n0 = (s << 12) + (b << 10) + p0;

    __shared__ float tile[256][17];

    const int cg = t >> 2;
    const int p4 = (t & 3) << 2;
#pragma unroll
    for (int pass = 0; pass < 4; ++pass) {
        const int c = cg + (pass << 6);
        const float4 v = *(const float4*)(src + (((size_t)((b << 8) + c)) << 10) + p0 + p4);
        tile[c][p4] = v.x; tile[c][p4 + 1] = v.y; tile[c][p4 + 2] = v.z; tile[c][p4 + 3] = v.w;
    }
    __syncthreads();

    const int r = t >> 4;
    const int q = t & 15;
    const int row = n0 + r;
    const int sw = (row >> 1) & 3;
    float nsum = 0.f;
#pragma unroll
    for (int h = 0; h < 2; ++h) {
        const int j = q + (h << 4);
        const int ck = j >> 2;
        const int sq = (j & 3) ^ sw;
        const int c0 = j << 3;
        uint pk[4];
#pragma unroll
        for (int jj = 0; jj < 4; ++jj) {
            const float f0 = tile[c0 + 2 * jj][r];
            const float f1 = tile[c0 + 2 * jj + 1][r];
            const __hip_bfloat16 h0 = __float2bfloat16(f0);
            const __hip_bfloat16 h1 = __float2bfloat16(f1);
            const float q0 = __bfloat162float(h0), q1 = __bfloat162float(h1);
            nsum = fmaf(q0, q0, nsum);
            nsum = fmaf(q1, q1, nsum);
            pk[jj] = (uint)(*(const ushort*)&h0) | ((uint)(*(const ushort*)&h1) << 16);
        }
        *(uint4*)(Zc + (size_t)ck * CKS + (size_t)row * 32 + (sq << 3)) =
            make_uint4(pk[0], pk[1], pk[2], pk[3]);
    }
#pragma unroll
    for (int off = 1; off < 16; off <<= 1) nsum += __shfl_xor(nsum, off, 32);
    if (q == 0) norms[row] = nsum;
}

// ---- GEMM: 2-wave blocks, 128x64 wave tiles, one 128x128 supertile/block ----
__global__ __launch_bounds__(128, 2) void gemm_epi(const ushort* __restrict__ Zc,
                                                   const float* __restrict__ norms,
                                                   const float* __restrict__ sigmas,
                                                   float* __restrict__ partials) {
    __shared__ float wsum[2];

    const int t = threadIdx.x;
    const int w = t >> 6, l = t & 63;
    const int m = l & 15, q = l >> 4;

    // panel decode: panels p of 8 super-columns; P(p) = 32p^2 + 4p blocks before
    // panel p; within panel, column-major (column tj2 has tj2+1 blocks).
    const int lin = blockIdx.x;
    int p = (int)((-4.0f + sqrtf(16.0f + 128.0f * (float)lin)) * (1.0f / 64.0f));
    p = p < 0 ? 0 : (p > 7 ? 7 : p);
    while (p < 7 && 32 * (p + 1) * (p + 1) + 4 * (p + 1) <= lin) ++p;
    while (p > 0 && 32 * p * p + 4 * p > lin) --p;
    const int o = lin - (32 * p * p + 4 * p);
    int c = 7;
#pragma unroll
    for (int cc = 7; cc >= 1; --cc) {
        const int Q = cc * (8 * p + 1) + (cc * (cc - 1)) / 2;
        if (o < Q) c = cc - 1;
    }
    const int Qc = c * (8 * p + 1) + (c * (c - 1)) / 2;
    const int tj2 = 8 * p + c;
    const int ti2 = o - Qc;              // 0..tj2
    const bool diag = (ti2 == tj2);

    const int i0 = ti2 << 7;                     // 128 rows
    const int jj0 = (tj2 << 7) + (w << 6);       // this wave's 64 cols

    int offA[8], offB[4];
#pragma unroll
    for (int f = 0; f < 8; ++f) {
        const int ra = i0 + (f << 4) + m;
        offA[f] = (ra << 5) + ((q ^ ((ra >> 1) & 3)) << 3);
    }
#pragma unroll
    for (int f = 0; f < 4; ++f) {
        const int rb = jj0 + (f << 4) + m;
        offB[f] = (rb << 5) + ((q ^ ((rb >> 1) & 3)) << 3);
    }

    floatx4 accf[8][4];
#pragma unroll
    for (int fi = 0; fi < 8; ++fi)
#pragma unroll
        for (int fj = 0; fj < 4; ++fj) accf[fi][fj] = (floatx4){0.f, 0.f, 0.f, 0.f};

    short8 curA[8], curB[4];
#pragma unroll
    for (int f = 0; f < 8; ++f) curA[f] = *(const short8*)(Zc + offA[f]);
#pragma unroll
    for (int f = 0; f < 4; ++f) curB[f] = *(const short8*)(Zc + offB[f]);

    // ---- main K loop: 8 chunks, 1-deep register prefetch ----
#pragma unroll
    for (int ck = 0; ck < 8; ++ck) {
        short8 nxtA[8], nxtB[4];
        if (ck < 7) {
            const size_t ko = (size_t)(ck + 1) * CKS;
#pragma unroll
            for (int f = 0; f < 8; ++f) nxtA[f] = *(const short8*)(Zc + ko + offA[f]);
#pragma unroll
            for (int f = 0; f < 4; ++f) nxtB[f] = *(const short8*)(Zc + ko + offB[f]);
        }
#pragma unroll
        for (int fi = 0; fi < 8; ++fi)
#pragma unroll
            for (int fj = 0; fj < 4; ++fj)
                accf[fi][fj] = __builtin_amdgcn_mfma_f32_16x16x32_bf16(curA[fi], curB[fj], accf[fi][fj], 0, 0, 0);
        if (ck < 7) {
#pragma unroll
            for (int f = 0; f < 8; ++f) curA[f] = nxtA[f];
#pragma unroll
            for (int f = 0; f < 4; ++f) curB[f] = nxtB[f];
        }
    }

    // ---- epilogue ----
    float c2[NSIG];
#pragma unroll
    for (int k = 0; k < NSIG; ++k) c2[k] = (-0.5f / sigmas[k]) * 1.44269504f;

    const float sgn2 = ((i0 < 4096) == (jj0 < 4096)) ? 2.f : -2.f;

    float njs[4];
#pragma unroll
    for (int fj = 0; fj < 4; ++fj) njs[fj] = norms[jj0 + (fj << 4) + m];

#pragma unroll
    for (int fi = 0; fi < 8; ++fi) {
        const floatx4 ni4 = *(const floatx4*)(norms + i0 + (fi << 4) + (q << 2));
#pragma unroll
        for (int fj = 0; fj < 4; ++fj) {
#pragma unroll
            for (int v = 0; v < 4; ++v) {
                float d = fmaf(-2.f, accf[fi][fj][v], ni4[v] + njs[fj]);
                d = fmaxf(d, 0.f);
                if (diag) {
                    // keep strictly-upper: (fi*16 + q*4 + v) < (w*64 + fj*16 + m)
                    const int dif = ((fi - fj) << 4) + ((q << 2) + v) - (w << 6) - m;
                    d = (dif < 0) ? d : 3.0e9f;
                }
                accf[fi][fj][v] = d;
            }
        }
    }

    float dmin = accf[0][0][0];
#pragma unroll
    for (int fi = 0; fi < 8; ++fi)
#pragma unroll
        for (int fj = 0; fj < 4; ++fj)
#pragma unroll
            for (int v = 0; v < 4; ++v) dmin = fminf(dmin, accf[fi][fj][v]);
#pragma unroll
    for (int off = 1; off < 64; off <<= 1) dmin = fminf(dmin, __shfl_xor(dmin, off, 64));

    float lsum = 0.f;
#pragma unroll
    for (int k = 0; k < NSIG; ++k) {
        if (c2[k] * dmin >= -126.f) {   // wave-uniform skip iff all exps underflow
#pragma unroll
            for (int fi = 0; fi < 8; ++fi)
#pragma unroll
                for (int fj = 0; fj < 4; ++fj)
#pragma unroll
                    for (int v = 0; v < 4; ++v)
                        lsum += __builtin_amdgcn_exp2f(c2[k] * accf[fi][fj][v]);
        }
    }
    lsum *= sgn2;

    // ---- block reduce + store ----
#pragma unroll
    for (int off = 32; off > 0; off >>= 1) lsum += __shfl_down(lsum, off, 64);
    if (l == 0) wsum[w] = lsum;
    __syncthreads();
    if (t == 0) partials[blockIdx.x] = wsum[0] + wsum[1];
}

__global__ __launch_bounds__(256) void finalize_kernel(const float* __restrict__ partials,
                                                       float* __restrict__ out) {
    __shared__ double sh[256];
    const int t = threadIdx.x;
    double s = 0.0;
    for (int i = t; i < NBLK2; i += 256) s += (double)partials[i];
    sh[t] = s;
    __syncthreads();
    for (int st = 128; st > 0; st >>= 1) {
        if (t < st) sh[t] += sh[t + st];
        __syncthreads();
    }
    if (t == 0) out[0] = (float)((sh[0] + 8192.0 * NSIG) * (1.0 / (4096.0 * 4096.0)));
}

extern "C" void kernel_launch(void* const* d_in, const int* in_sizes, int n_in,
                              void* d_out, int out_size, void* d_ws, size_t ws_size,
                              hipStream_t stream) {
    const float* x   = (const float*)d_in[0];
    const float* y   = (const float*)d_in[1];
    const float* sig = (const float*)d_in[2];

    ushort* Zc      = (ushort*)d_ws;                                   // 4 MiB
    float* norms    = (float*)((char*)d_ws + (size_t)8192 * 256 * 2);  // 32 KiB
    float* partials = (float*)((char*)norms + 8192 * sizeof(float));   // 2080 floats
    float* out      = (float*)d_out;

    prep_kernel<<<512, 256, 0, stream>>>(x, y, Zc, norms);
    gemm_epi<<<NBLK2, 128, 0, stream>>>(Zc, norms, sig, partials);
    finalize_kernel<<<1, 256, 0, stream>>>(partials, out);
}

// Round 5
// 99.453 us; speedup vs baseline: 1.1248x; 1.1248x over previous
//
#include <hip/hip_runtime.h>
#include <hip/hip_bf16.h>

// MMD loss via bf16 MFMA Gram matrix — barrier-free LDS-free GEMM core.
// R5: R2 structure + depth-2 chunk prefetch. Occupancy discovery: unified
// VGPR (arch+acc) ~148/wave puts us at 2 waves/SIMD (m69 steps 64/128/256);
// R1's 24.6% occupancy == exactly 2 blocks/CU, and launch_bounds(,3) never
// bound. R4 (256 unified) fell below -> latency exposed -> +12us regression.
// At 2 waves/SIMD each wave owns up to 256 unified regs; R2 used 148. Spend
// the free headroom on ILP: 3 rotating fragment sets (depth-2 prefetch,
// ~190 unified), cover 2x77cyc MFMA x 2 waves ~ 300cyc >= L2 latency.
// Cross-tile prologue now issues next tile's chunks 0 AND 1 under epilogue.
//
// R2: persistent grid (694 blocks), cross-tile prologue under epilogue,
// norms loaded before prologue so epilogue waitcnt doesn't drain prefetch.
// Zc layout: Zc[ck][row][32], stored quad = q ^ ((row>>1)&3).
// Lessons: no __threadfence; no forced occupancy past spill; no scattered
// vector loads; no per-chunk s_barrier alignment (R3: +3.4us); no 128x64
// wave tiles at 1 wave/SIMD (R4: +12us).
//
// z = [xf; yf] (8192 x 256). result = (1/4096^2)*(8192*NSIG + sum_{i<j} 2 s_i s_j K_ij)
// ws: [0,4MiB) bf16 Zc; float norms[8192]; float partials[694].

#define NSIG 5
#define CKS   262144                 // chunk stride in ushorts: 8192 rows * 32
#define NBLK2 2080                   // 64-supergrid triangle: 64*65/2
#define GRIDP 694                    // persistent grid: 692 blocks x3 tiles + 2 x2

typedef __attribute__((ext_vector_type(8))) short short8;
typedef __attribute__((ext_vector_type(4))) float floatx4;

// ---- prep: (B,C,H,W) fp32 -> Zc chunked-swizzled bf16 + norms (unchanged) ----
__global__ __launch_bounds__(256) void prep_kernel(const float* __restrict__ x,
                                                   const float* __restrict__ y,
                                                   ushort* __restrict__ Zc,
                                                   float* __restrict__ norms) {
    const int bid = blockIdx.x;           // s(1) | b(2) | strip(6)
    const int t = threadIdx.x;
    const int s = bid >> 8;
    const int b = (bid >> 6) & 3;
    const int p0 = (bid & 63) << 4;
    const float* src = s ? y : x;
    const int n0 = (s << 12) + (b << 10) + p0;

    __shared__ float tile[256][17];

    const int cg = t >> 2;
    const int p4 = (t & 3) << 2;
#pragma unroll
    for (int pass = 0; pass < 4; ++pass) {
        const int c = cg + (pass << 6);
        const float4 v = *(const float4*)(src + (((size_t)((b << 8) + c)) << 10) + p0 + p4);
        tile[c][p4] = v.x; tile[c][p4 + 1] = v.y; tile[c][p4 + 2] = v.z; tile[c][p4 + 3] = v.w;
    }
    __syncthreads();

    const int r = t >> 4;
    const int q = t & 15;
    const int row = n0 + r;
    const int sw = (row >> 1) & 3;
    float nsum = 0.f;
#pragma unroll
    for (int h = 0; h < 2; ++h) {
        const int j = q + (h << 4);
        const int ck = j >> 2;
        const int sq = (j & 3) ^ sw;
        const int c0 = j << 3;
        uint pk[4];
#pragma unroll
        for (int jj = 0; jj < 4; ++jj) {
            const float f0 = tile[c0 + 2 * jj][r];
            const float f1 = tile[c0 + 2 * jj + 1][r];
            const __hip_bfloat16 h0 = __float2bfloat16(f0);
            const __hip_bfloat16 h1 = __float2bfloat16(f1);
            const float q0 = __bfloat162float(h0), q1 = __bfloat162float(h1);
            nsum = fmaf(q0, q0, nsum);
            nsum = fmaf(q1, q1, nsum);
            pk[jj] = (uint)(*(const ushort*)&h0) | ((uint)(*(const ushort*)&h1) << 16);
        }
        *(uint4*)(Zc + (size_t)ck * CKS + (size_t)row * 32 + (sq << 3)) =
            make_uint4(pk[0], pk[1], pk[2], pk[3]);
    }
#pragma unroll
    for (int off = 1; off < 16; off <<= 1) nsum += __shfl_xor(nsum, off, 32);
    if (q == 0) norms[row] = nsum;
}

// ---- tile decode: panel-ordered triangle (unchanged math) ----
__device__ __forceinline__ void decode_tile(int lin, int w, int& i0, int& j0,
                                            bool& active, bool& diag) {
    int p = (int)((-4.0f + sqrtf(16.0f + 128.0f * (float)lin)) * (1.0f / 64.0f));
    p = p < 0 ? 0 : (p > 7 ? 7 : p);
    while (p < 7 && 32 * (p + 1) * (p + 1) + 4 * (p + 1) <= lin) ++p;
    while (p > 0 && 32 * p * p + 4 * p > lin) --p;
    const int o = lin - (32 * p * p + 4 * p);
    int c = 7;
#pragma unroll
    for (int cc = 7; cc >= 1; --cc) {
        const int Q = cc * (8 * p + 1) + (cc * (cc - 1)) / 2;
        if (o < Q) c = cc - 1;
    }
    const int Qc = c * (8 * p + 1) + (c * (c - 1)) / 2;
    const int tj2 = 8 * p + c;
    const int ti2 = o - Qc;              // 0..tj2
    const int ti = (ti2 << 1) + (w >> 1);
    const int tj = (tj2 << 1) + (w & 1);
    active = (ti <= tj);
    diag = (ti == tj);
    i0 = ti << 6;
    j0 = tj << 6;
}

__device__ __forceinline__ void tile_offsets(int i0, int j0, int m, int q,
                                             int* offA, int* offB) {
#pragma unroll
    for (int f = 0; f < 4; ++f) {
        const int ra = i0 + (f << 4) + m;
        offA[f] = (ra << 5) + ((q ^ ((ra >> 1) & 3)) << 3);
        const int rb = j0 + (f << 4) + m;
        offB[f] = (rb << 5) + ((q ^ ((rb >> 1) & 3)) << 3);
    }
}

// ---- GEMM: persistent 2x2 wave-tile blocks, depth-2 chunk prefetch ----
__global__ __launch_bounds__(256, 2) void gemm_epi(const ushort* __restrict__ Zc,
                                                   const float* __restrict__ norms,
                                                   const float* __restrict__ sigmas,
                                                   float* __restrict__ partials) {
    __shared__ float wsum[4];

    const int t = threadIdx.x;
    const int w = t >> 6, l = t & 63;
    const int m = l & 15, q = l >> 4;

    float c2[NSIG];
#pragma unroll
    for (int k = 0; k < NSIG; ++k) c2[k] = (-0.5f / sigmas[k]) * 1.44269504f;

    int lin = blockIdx.x;
    int i0, j0;
    bool active, diag;
    decode_tile(lin, w, i0, j0, active, diag);
    int offA[4], offB[4];
    tile_offsets(i0, j0, m, q, offA, offB);

    // depth-2 pipeline registers: A0/B0 = chunk ck, A1/B1 = chunk ck+1
    short8 A0[4], B0[4], A1[4], B1[4];
#pragma unroll
    for (int f = 0; f < 4; ++f) {
        A0[f] = *(const short8*)(Zc + offA[f]);
        B0[f] = *(const short8*)(Zc + offB[f]);
    }
#pragma unroll
    for (int f = 0; f < 4; ++f) {
        A1[f] = *(const short8*)(Zc + CKS + offA[f]);
        B1[f] = *(const short8*)(Zc + CKS + offB[f]);
    }

    float lsum = 0.f;

#pragma unroll 1
    for (;;) {
        floatx4 accf[4][4];
#pragma unroll
        for (int fi = 0; fi < 4; ++fi)
#pragma unroll
            for (int fj = 0; fj < 4; ++fj) accf[fi][fj] = (floatx4){0.f, 0.f, 0.f, 0.f};

        // ---- main K loop: 8 chunks, depth-2 register prefetch ----
#pragma unroll
        for (int ck = 0; ck < 8; ++ck) {
            short8 ldA[4], ldB[4];
            if (ck < 6) {
                const size_t ko = (size_t)(ck + 2) * CKS;
#pragma unroll
                for (int f = 0; f < 4; ++f) {
                    ldA[f] = *(const short8*)(Zc + ko + offA[f]);
                    ldB[f] = *(const short8*)(Zc + ko + offB[f]);
                }
            }
#pragma unroll
            for (int fi = 0; fi < 4; ++fi)
#pragma unroll
                for (int fj = 0; fj < 4; ++fj)
                    accf[fi][fj] = __builtin_amdgcn_mfma_f32_16x16x32_bf16(A0[fi], B0[fj], accf[fi][fj], 0, 0, 0);
            if (ck < 7) {
#pragma unroll
                for (int f = 0; f < 4; ++f) { A0[f] = A1[f]; B0[f] = B1[f]; }
            }
            if (ck < 6) {
#pragma unroll
                for (int f = 0; f < 4; ++f) { A1[f] = ldA[f]; B1[f] = ldB[f]; }
            }
        }

        // ---- save current-tile epilogue context ----
        const int ei0 = i0, ej0 = j0;
        const bool eact = active, ediag = diag;
        const float esgn2 = ((ei0 < 4096) == (ej0 < 4096)) ? 2.f : -2.f;

        // ---- norms FIRST (retire before prologue loads; epilogue waitcnt
        //      then leaves the next-tile prefetch in flight) ----
        floatx4 ni4[4];
        float njs[4];
#pragma unroll
        for (int fi = 0; fi < 4; ++fi)
            ni4[fi] = *(const floatx4*)(norms + ei0 + (fi << 4) + (q << 2));
#pragma unroll
        for (int fj = 0; fj < 4; ++fj)
            njs[fj] = norms[ej0 + (fj << 4) + m];

        // ---- issue next tile's chunk-0 AND chunk-1 under this epilogue ----
        const int lin2 = lin + GRIDP;
        const bool have2 = (lin2 < NBLK2);
        if (have2) {
            decode_tile(lin2, w, i0, j0, active, diag);
            tile_offsets(i0, j0, m, q, offA, offB);
#pragma unroll
            for (int f = 0; f < 4; ++f) {
                A0[f] = *(const short8*)(Zc + offA[f]);
                B0[f] = *(const short8*)(Zc + offB[f]);
            }
#pragma unroll
            for (int f = 0; f < 4; ++f) {
                A1[f] = *(const short8*)(Zc + CKS + offA[f]);
                B1[f] = *(const short8*)(Zc + CKS + offB[f]);
            }
        }

        // ---- epilogue (wave-uniform active flag) ----
        if (eact) {
#pragma unroll
            for (int fi = 0; fi < 4; ++fi) {
#pragma unroll
                for (int fj = 0; fj < 4; ++fj) {
#pragma unroll
                    for (int v = 0; v < 4; ++v) {
                        float d = fmaf(-2.f, accf[fi][fj][v], ni4[fi][v] + njs[fj]);
                        d = fmaxf(d, 0.f);
                        if (ediag) {
                            const int dif = ((fi - fj) << 4) + ((q << 2) + v) - m;   // gi - gj
                            d = (dif < 0) ? d : 3.0e9f;    // strictly-upper only
                        }
                        accf[fi][fj][v] = d;
                    }
                }
            }

            float dmin = accf[0][0][0];
#pragma unroll
            for (int fi = 0; fi < 4; ++fi)
#pragma unroll
                for (int fj = 0; fj < 4; ++fj)
#pragma unroll
                    for (int v = 0; v < 4; ++v) dmin = fminf(dmin, accf[fi][fj][v]);
#pragma unroll
            for (int off = 1; off < 64; off <<= 1) dmin = fminf(dmin, __shfl_xor(dmin, off, 64));

            float tsum = 0.f;
#pragma unroll
            for (int k = 0; k < NSIG; ++k) {
                if (c2[k] * dmin >= -126.f) {   // wave-uniform skip iff all exps underflow
#pragma unroll
                    for (int fi = 0; fi < 4; ++fi)
#pragma unroll
                        for (int fj = 0; fj < 4; ++fj)
#pragma unroll
                            for (int v = 0; v < 4; ++v)
                                tsum += __builtin_amdgcn_exp2f(c2[k] * accf[fi][fj][v]);
                }
            }
            lsum = fmaf(esgn2, tsum, lsum);
        }

        lin = lin2;
        if (!have2) break;
    }

    // ---- once-per-block reduce + store ----
#pragma unroll
    for (int off = 32; off > 0; off >>= 1) lsum += __shfl_down(lsum, off, 64);
    if (l == 0) wsum[w] = lsum;
    __syncthreads();
    if (t == 0) partials[blockIdx.x] = wsum[0] + wsum[1] + wsum[2] + wsum[3];
}

__global__ __launch_bounds__(256) void finalize_kernel(const float* __restrict__ partials,
                                                       float* __restrict__ out) {
    __shared__ double sh[256];
    const int t = threadIdx.x;
    double s = 0.0;
    for (int i = t; i < GRIDP; i += 256) s += (double)partials[i];
    sh[t] = s;
    __syncthreads();
    for (int st = 128; st > 0; st >>= 1) {
        if (t < st) sh[t] += sh[t + st];
        __syncthreads();
    }
    if (t == 0) out[0] = (float)((sh[0] + 8192.0 * NSIG) * (1.0 / (4096.0 * 4096.0)));
}

extern "C" void kernel_launch(void* const* d_in, const int* in_sizes, int n_in,
                              void* d_out, int out_size, void* d_ws, size_t ws_size,
                              hipStream_t stream) {
    const float* x   = (const float*)d_in[0];
    const float* y   = (const float*)d_in[1];
    const float* sig = (const float*)d_in[2];

    ushort* Zc      = (ushort*)d_ws;                                   // 4 MiB
    float* norms    = (float*)((char*)d_ws + (size_t)8192 * 256 * 2);  // 32 KiB
    float* partials = (float*)((char*)norms + 8192 * sizeof(float));   // 694 floats
    float* out      = (float*)d_out;

    prep_kernel<<<512, 256, 0, stream>>>(x, y, Zc, norms);
    gemm_epi<<<GRIDP, 256, 0, stream>>>(Zc, norms, sig, partials);
    finalize_kernel<<<1, 256, 0, stream>>>(partials, out);
}

// Round 7
// 96.858 us; speedup vs baseline: 1.1549x; 1.0268x over previous
//
#include <hip/hip_runtime.h>
#include <hip/hip_bf16.h>

// MMD loss via bf16 MFMA Gram matrix.
// R6: LDS-staged block-shared panels. Evidence R1/R4/R5: gemm wall ~45us is
// insensitive to occupancy (24.6%->14.7%), prefetch depth (1->2), and -25%
// traffic; delivered fragment BW pinned ~11.7 TB/s (Zc 4MiB == per-XCD L2
// size; harness's 256MB fill wipes caches each iter; FETCH 16.8MB shows HBM
// re-fetch). => delivered-BW bound with 2x duplicated demand (each line
// fetched once per wave pair). Fix: stage each chunk's contiguous 8KB A/B
// panels into LDS once per block (global_load_lds w16, double-buffered, one
// __syncthreads per chunk); 4 waves ds_read fragments. Traffic 532->266MB at
// unchanged occupancy. Diagonal supertiles stage A only (B aliases it).
//
// Zc layout: Zc[ck][row][32], stored quad = q ^ ((row>>1)&3); panel for 128
// rows is one contiguous 8KB block; supertile base I0 % 128 == 0 keeps the
// swizzle formula valid on LDS-local row indices.
// Lessons: no __threadfence; no forced occupancy past spill; no scattered
// vector loads; no per-chunk s_barrier alignment of register streams (R3);
// no 128x64 wave tiles at 1 wave/SIMD (R4); depth-2 reg prefetch neutral (R5).
//
// z = [xf; yf] (8192 x 256). result = (1/4096^2)*(8192*NSIG + sum_{i<j} 2 s_i s_j K_ij)
// ws: [0,4MiB) bf16 Zc; float norms[8192]; float partials[2080].

#define NSIG 5
#define CKS   262144                 // chunk stride in ushorts: 8192 rows * 32
#define NBLK2 2080                   // 64-supergrid triangle: 64*65/2

typedef __attribute__((ext_vector_type(8))) short short8;
typedef __attribute__((ext_vector_type(4))) float floatx4;

#define GLDS16(gp, lp) __builtin_amdgcn_global_load_lds( \
    (const __attribute__((address_space(1))) void*)(gp),  \
    (__attribute__((address_space(3))) void*)(lp), 16, 0, 0)

// ---- prep: (B,C,H,W) fp32 -> Zc chunked-swizzled bf16 + norms (unchanged) ----
__global__ __launch_bounds__(256) void prep_kernel(const float* __restrict__ x,
                                                   const float* __restrict__ y,
                                                   ushort* __restrict__ Zc,
                                                   float* __restrict__ norms) {
    const int bid = blockIdx.x;           // s(1) | b(2) | strip(6)
    const int t = threadIdx.x;
    const int s = bid >> 8;
    const int b = (bid >> 6) & 3;
    const int p0 = (bid & 63) << 4;
    const float* src = s ? y : x;
    const int n0 = (s << 12) + (b << 10) + p0;

    __shared__ float tile[256][17];

    const int cg = t >> 2;
    const int p4 = (t & 3) << 2;
#pragma unroll
    for (int pass = 0; pass < 4; ++pass) {
        const int c = cg + (pass << 6);
        const float4 v = *(const float4*)(src + (((size_t)((b << 8) + c)) << 10) + p0 + p4);
        tile[c][p4] = v.x; tile[c][p4 + 1] = v.y; tile[c][p4 + 2] = v.z; tile[c][p4 + 3] = v.w;
    }
    __syncthreads();

    const int r = t >> 4;
    const int q = t & 15;
    const int row = n0 + r;
    const int sw = (row >> 1) & 3;
    float nsum = 0.f;
#pragma unroll
    for (int h = 0; h < 2; ++h) {
        const int j = q + (h << 4);
        const int ck = j >> 2;
        const int sq = (j & 3) ^ sw;
        const int c0 = j << 3;
        uint pk[4];
#pragma unroll
        for (int jj = 0; jj < 4; ++jj) {
            const float f0 = tile[c0 + 2 * jj][r];
            const float f1 = tile[c0 + 2 * jj + 1][r];
            const __hip_bfloat16 h0 = __float2bfloat16(f0);
            const __hip_bfloat16 h1 = __float2bfloat16(f1);
            const float q0 = __bfloat162float(h0), q1 = __bfloat162float(h1);
            nsum = fmaf(q0, q0, nsum);
            nsum = fmaf(q1, q1, nsum);
            pk[jj] = (uint)(*(const ushort*)&h0) | ((uint)(*(const ushort*)&h1) << 16);
        }
        *(uint4*)(Zc + (size_t)ck * CKS + (size_t)row * 32 + (sq << 3)) =
            make_uint4(pk[0], pk[1], pk[2], pk[3]);
    }
#pragma unroll
    for (int off = 1; off < 16; off <<= 1) nsum += __shfl_xor(nsum, off, 32);
    if (q == 0) norms[row] = nsum;
}

// ---- GEMM: 4-wave blocks, 128x128 supertile, LDS-staged shared panels ----
__global__ __launch_bounds__(256, 2) void gemm_epi(const ushort* __restrict__ Zc,
                                                   const float* __restrict__ norms,
                                                   const float* __restrict__ sigmas,
                                                   float* __restrict__ partials) {
    __shared__ ushort bufA[2][4096];   // 2 x 8KB: A panel (128 rows x 32)
    __shared__ ushort bufB[2][4096];   // 2 x 8KB: B panel
    __shared__ float wsum[4];

    const int t = threadIdx.x;
    const int w = t >> 6, l = t & 63;
    const int m = l & 15, q = l >> 4;

    // panel decode: panels p of 8 super-columns; P(p) = 32p^2 + 4p blocks before
    // panel p; within panel, column-major (column tj2 has tj2+1 blocks).
    const int lin = blockIdx.x;
    int p = (int)((-4.0f + sqrtf(16.0f + 128.0f * (float)lin)) * (1.0f / 64.0f));
    p = p < 0 ? 0 : (p > 7 ? 7 : p);
    while (p < 7 && 32 * (p + 1) * (p + 1) + 4 * (p + 1) <= lin) ++p;
    while (p > 0 && 32 * p * p + 4 * p > lin) --p;
    const int o = lin - (32 * p * p + 4 * p);
    int c = 7;
#pragma unroll
    for (int cc = 7; cc >= 1; --cc) {
        const int Q = cc * (8 * p + 1) + (cc * (cc - 1)) / 2;
        if (o < Q) c = cc - 1;
    }
    const int Qc = c * (8 * p + 1) + (c * (c - 1)) / 2;
    const int tj2 = 8 * p + c;
    const int ti2 = o - Qc;              // 0..tj2
    const bool diagST = (ti2 == tj2);    // supertile on diagonal: B panel == A panel

    const int I0 = ti2 << 7;             // supertile row base (multiple of 128)
    const int J0 = tj2 << 7;

    // wave quadrant: ti = 2*ti2 + (w>>1), tj = 2*tj2 + (w&1)
    const int ti = (ti2 << 1) + (w >> 1);
    const int tj = (tj2 << 1) + (w & 1);
    const bool active = (ti <= tj);      // lower-tri wave of diag supertile: discard
    const bool diag = (ti == tj);
    const int i0 = ti << 6, j0 = tj << 6;       // global bases (norms, sign, mask)

    // LDS fragment read offsets (ushort idx). LDS row r == global row - panel base;
    // panel base % 128 == 0 so swizzle formula is valid on r directly.
    int loffA[4], loffB[4];
#pragma unroll
    for (int f = 0; f < 4; ++f) {
        const int ra = ((w >> 1) << 6) + (f << 4) + m;
        loffA[f] = (ra << 5) + ((q ^ ((ra >> 1) & 3)) << 3);
        const int rb = ((w & 1) << 6) + (f << 4) + m;
        loffB[f] = (rb << 5) + ((q ^ ((rb >> 1) & 3)) << 3);
    }

    // staging: wave w copies bytes [w*2048, (w+1)*2048) of each 8KB panel,
    // two 1KB wave-issues each; lane offset l*16B handled by HW (lds = base+lane*16).
    const int sg = (w << 10) + (l << 3);        // ushort src offset, issue 0
    const ushort* gA0 = Zc + (size_t)I0 * 32 + sg;
    const ushort* gB0 = Zc + (size_t)J0 * 32 + sg;
    ushort* lA = &bufA[0][w << 10];             // wave-uniform LDS bases (half 0)
    ushort* lB = &bufB[0][w << 10];

    // prologue: stage chunk 0 into half 0
    GLDS16(gA0, lA);
    GLDS16(gA0 + 512, lA + 512);
    if (!diagST) {
        GLDS16(gB0, lB);
        GLDS16(gB0 + 512, lB + 512);
    }
    __syncthreads();

    floatx4 accf[4][4];
#pragma unroll
    for (int fi = 0; fi < 4; ++fi)
#pragma unroll
        for (int fj = 0; fj < 4; ++fj) accf[fi][fj] = (floatx4){0.f, 0.f, 0.f, 0.f};

    // ---- main K loop: 8 chunks, LDS double-buffered, 1 barrier per chunk ----
#pragma unroll
    for (int ck = 0; ck < 8; ++ck) {
        const int half = ck & 1;
        if (ck < 7) {
            const size_t ko = (size_t)(ck + 1) * CKS;
            ushort* nA = &bufA[half ^ 1][w << 10];
            GLDS16(gA0 + ko, nA);
            GLDS16(gA0 + ko + 512, nA + 512);
            if (!diagST) {
                ushort* nB = &bufB[half ^ 1][w << 10];
                GLDS16(gB0 + ko, nB);
                GLDS16(gB0 + ko + 512, nB + 512);
            }
        }
        const ushort* rA = &bufA[half][0];
        const ushort* rB = diagST ? &bufA[half][0] : &bufB[half][0];
        short8 fa[4], fb[4];
#pragma unroll
        for (int f = 0; f < 4; ++f) fa[f] = *(const short8*)(rA + loffA[f]);
#pragma unroll
        for (int f = 0; f < 4; ++f) fb[f] = *(const short8*)(rB + loffB[f]);
#pragma unroll
        for (int fi = 0; fi < 4; ++fi)
#pragma unroll
            for (int fj = 0; fj < 4; ++fj)
                accf[fi][fj] = __builtin_amdgcn_mfma_f32_16x16x32_bf16(fa[fi], fb[fj], accf[fi][fj], 0, 0, 0);
        __syncthreads();   // drains this wave's ds_reads + staged glds (vmcnt)
    }

    // ---- epilogue (barrier-free; inactive wave skips, reconverges at reduce) ----
    float lsum = 0.f;
    if (active) {
        float c2[NSIG];
#pragma unroll
        for (int k = 0; k < NSIG; ++k) c2[k] = (-0.5f / sigmas[k]) * 1.44269504f;

        const float sgn2 = ((i0 < 4096) == (j0 < 4096)) ? 2.f : -2.f;

        float njs[4];
#pragma unroll
        for (int fj = 0; fj < 4; ++fj) njs[fj] = norms[j0 + (fj << 4) + m];

#pragma unroll
        for (int fi = 0; fi < 4; ++fi) {
            const floatx4 ni4 = *(const floatx4*)(norms + i0 + (fi << 4) + (q << 2));
#pragma unroll
            for (int fj = 0; fj < 4; ++fj) {
#pragma unroll
                for (int v = 0; v < 4; ++v) {
                    float d = fmaf(-2.f, accf[fi][fj][v], ni4[v] + njs[fj]);
                    d = fmaxf(d, 0.f);
                    if (diag) {
                        const int dif = ((fi - fj) << 4) + ((q << 2) + v) - m;   // gi - gj
                        d = (dif < 0) ? d : 3.0e9f;    // strictly-upper only
                    }
                    accf[fi][fj][v] = d;
                }
            }
        }

        float dmin = accf[0][0][0];
#pragma unroll
        for (int fi = 0; fi < 4; ++fi)
#pragma unroll
            for (int fj = 0; fj < 4; ++fj)
#pragma unroll
                for (int v = 0; v < 4; ++v) dmin = fminf(dmin, accf[fi][fj][v]);
#pragma unroll
        for (int off = 1; off < 64; off <<= 1) dmin = fminf(dmin, __shfl_xor(dmin, off, 64));

        float tsum = 0.f;
#pragma unroll
        for (int k = 0; k < NSIG; ++k) {
            if (c2[k] * dmin >= -126.f) {   // wave-uniform skip iff all exps underflow
#pragma unroll
                for (int fi = 0; fi < 4; ++fi)
#pragma unroll
                    for (int fj = 0; fj < 4; ++fj)
#pragma unroll
                        for (int v = 0; v < 4; ++v)
                            tsum += __builtin_amdgcn_exp2f(c2[k] * accf[fi][fj][v]);
            }
        }
        lsum = sgn2 * tsum;
    }

    // ---- block reduce + store ----
#pragma unroll
    for (int off = 32; off > 0; off >>= 1) lsum += __shfl_down(lsum, off, 64);
    if (l == 0) wsum[w] = lsum;
    __syncthreads();
    if (t == 0) partials[blockIdx.x] = wsum[0] + wsum[1] + wsum[2] + wsum[3];
}

__global__ __launch_bounds__(256) void finalize_kernel(const float* __restrict__ partials,
                                                       float* __restrict__ out) {
    __shared__ double sh[256];
    const int t = threadIdx.x;
    double s = 0.0;
    for (int i = t; i < NBLK2; i += 256) s += (double)partials[i];
    sh[t] = s;
    __syncthreads();
    for (int st = 128; st > 0; st >>= 1) {
        if (t < st) sh[t] += sh[t + st];
        __syncthreads();
    }
    if (t == 0) out[0] = (float)((sh[0] + 8192.0 * NSIG) * (1.0 / (4096.0 * 4096.0)));
}

extern "C" void kernel_launch(void* const* d_in, const int* in_sizes, int n_in,
                              void* d_out, int out_size, void* d_ws, size_t ws_size,
                              hipStream_t stream) {
    const float* x   = (const float*)d_in[0];
    const float* y   = (const float*)d_in[1];
    const float* sig = (const float*)d_in[2];

    ushort* Zc      = (ushort*)d_ws;                                   // 4 MiB
    float* norms    = (float*)((char*)d_ws + (size_t)8192 * 256 * 2);  // 32 KiB
    float* partials = (float*)((char*)norms + 8192 * sizeof(float));   // 2080 floats
    float* out      = (float*)d_out;

    prep_kernel<<<512, 256, 0, stream>>>(x, y, Zc, norms);
    gemm_epi<<<NBLK2, 256, 0, stream>>>(Zc, norms, sig, partials);
    finalize_kernel<<<1, 256, 0, stream>>>(partials, out);
}

// Round 8
// 95.697 us; speedup vs baseline: 1.1689x; 1.0121x over previous
//
#include <hip/hip_runtime.h>
#include <hip/hip_bf16.h>

// MMD loss via bf16 MFMA Gram matrix.
// R8: counted-vmcnt software pipeline (T3/T4). R7 proved traffic is NOT the
// binder (halved traffic, zero delta). The invariant across all neutral
// variants: every chunk ends in a full vmcnt(0) drain (__syncthreads), which
// exposes ~500cy glds latency per chunk with only ~130cy of MFMA cover.
// Fix: 3-buffer LDS, glds issued at depth-2 (ck+2), and per-chunk
// {s_waitcnt vmcnt(4) (waits only ck+1's 4 glds, leaves ck+2's in flight)
// + raw s_barrier + sched_barrier(0)}. B panel always staged (uniform
// 4 glds/wave/chunk so the vmcnt immediate is uniform; diagonal supertiles
// stage duplicate data, 64/2080 blocks, negligible).
//
// Zc layout: Zc[ck][row][32], stored quad = q ^ ((row>>1)&3); panel for 128
// rows is one contiguous 8KB block; supertile base % 128 == 0 keeps the
// swizzle valid on LDS-local rows. glds: wave-uniform LDS base + lane*16B.
// Lessons: no __threadfence; no forced occupancy past spill; no scattered
// vector loads; no s_barrier alignment of register streams (R3); no 128x64
// tiles at 1 wave/SIMD (R4); reg depth-2 neutral (R5); traffic halving
// neutral (R7) -> delivered-BW theory dead.
//
// z = [xf; yf] (8192 x 256). result = (1/4096^2)*(8192*NSIG + sum_{i<j} 2 s_i s_j K_ij)
// ws: [0,4MiB) bf16 Zc; float norms[8192]; float partials[2080].

#define NSIG 5
#define CKS   262144                 // chunk stride in ushorts: 8192 rows * 32
#define NBLK2 2080                   // 64-supergrid triangle: 64*65/2

typedef __attribute__((ext_vector_type(8))) short short8;
typedef __attribute__((ext_vector_type(4))) float floatx4;

#define GLDS16(gp, lp) __builtin_amdgcn_global_load_lds( \
    (const __attribute__((address_space(1))) void*)(gp),  \
    (__attribute__((address_space(3))) void*)(lp), 16, 0, 0)

#define WAITVM4 asm volatile("s_waitcnt vmcnt(4)" ::: "memory")
#define WAITVM0 asm volatile("s_waitcnt vmcnt(0)" ::: "memory")

// ---- prep: (B,C,H,W) fp32 -> Zc chunked-swizzled bf16 + norms (unchanged) ----
__global__ __launch_bounds__(256) void prep_kernel(const float* __restrict__ x,
                                                   const float* __restrict__ y,
                                                   ushort* __restrict__ Zc,
                                                   float* __restrict__ norms) {
    const int bid = blockIdx.x;           // s(1) | b(2) | strip(6)
    const int t = threadIdx.x;
    const int s = bid >> 8;
    const int b = (bid >> 6) & 3;
    const int p0 = (bid & 63) << 4;
    const float* src = s ? y : x;
    const int n0 = (s << 12) + (b << 10) + p0;

    __shared__ float tile[256][17];

    const int cg = t >> 2;
    const int p4 = (t & 3) << 2;
#pragma unroll
    for (int pass = 0; pass < 4; ++pass) {
        const int c = cg + (pass << 6);
        const float4 v = *(const float4*)(src + (((size_t)((b << 8) + c)) << 10) + p0 + p4);
        tile[c][p4] = v.x; tile[c][p4 + 1] = v.y; tile[c][p4 + 2] = v.z; tile[c][p4 + 3] = v.w;
    }
    __syncthreads();

    const int r = t >> 4;
    const int q = t & 15;
    const int row = n0 + r;
    const int sw = (row >> 1) & 3;
    float nsum = 0.f;
#pragma unroll
    for (int h = 0; h < 2; ++h) {
        const int j = q + (h << 4);
        const int ck = j >> 2;
        const int sq = (j & 3) ^ sw;
        const int c0 = j << 3;
        uint pk[4];
#pragma unroll
        for (int jj = 0; jj < 4; ++jj) {
            const float f0 = tile[c0 + 2 * jj][r];
            const float f1 = tile[c0 + 2 * jj + 1][r];
            const __hip_bfloat16 h0 = __float2bfloat16(f0);
            const __hip_bfloat16 h1 = __float2bfloat16(f1);
            const float q0 = __bfloat162float(h0), q1 = __bfloat162float(h1);
            nsum = fmaf(q0, q0, nsum);
            nsum = fmaf(q1, q1, nsum);
            pk[jj] = (uint)(*(const ushort*)&h0) | ((uint)(*(const ushort*)&h1) << 16);
        }
        *(uint4*)(Zc + (size_t)ck * CKS + (size_t)row * 32 + (sq << 3)) =
            make_uint4(pk[0], pk[1], pk[2], pk[3]);
    }
#pragma unroll
    for (int off = 1; off < 16; off <<= 1) nsum += __shfl_xor(nsum, off, 32);
    if (q == 0) norms[row] = nsum;
}

// ---- GEMM: 4-wave blocks, 128x128 supertile, 3-buffer counted-vmcnt pipe ----
__global__ __launch_bounds__(256) void gemm_epi(const ushort* __restrict__ Zc,
                                                const float* __restrict__ norms,
                                                const float* __restrict__ sigmas,
                                                float* __restrict__ partials) {
    __shared__ ushort bufA[3][4096];   // 3 x 8KB: A panel (128 rows x 32)
    __shared__ ushort bufB[3][4096];   // 3 x 8KB: B panel
    __shared__ float wsum[4];

    const int t = threadIdx.x;
    const int w = t >> 6, l = t & 63;
    const int m = l & 15, q = l >> 4;

    // panel decode: panels p of 8 super-columns; P(p) = 32p^2 + 4p blocks before
    // panel p; within panel, column-major (column tj2 has tj2+1 blocks).
    const int lin = blockIdx.x;
    int p = (int)((-4.0f + sqrtf(16.0f + 128.0f * (float)lin)) * (1.0f / 64.0f));
    p = p < 0 ? 0 : (p > 7 ? 7 : p);
    while (p < 7 && 32 * (p + 1) * (p + 1) + 4 * (p + 1) <= lin) ++p;
    while (p > 0 && 32 * p * p + 4 * p > lin) --p;
    const int o = lin - (32 * p * p + 4 * p);
    int c = 7;
#pragma unroll
    for (int cc = 7; cc >= 1; --cc) {
        const int Q = cc * (8 * p + 1) + (cc * (cc - 1)) / 2;
        if (o < Q) c = cc - 1;
    }
    const int Qc = c * (8 * p + 1) + (c * (c - 1)) / 2;
    const int tj2 = 8 * p + c;
    const int ti2 = o - Qc;              // 0..tj2

    const int I0 = ti2 << 7;             // supertile bases (multiples of 128)
    const int J0 = tj2 << 7;

    // wave quadrant: ti = 2*ti2 + (w>>1), tj = 2*tj2 + (w&1)
    const int ti = (ti2 << 1) + (w >> 1);
    const int tj = (tj2 << 1) + (w & 1);
    const bool active = (ti <= tj);      // lower-tri wave of diag supertile: discard
    const bool diag = (ti == tj);
    const int i0 = ti << 6, j0 = tj << 6;

    // LDS fragment read offsets (ushort idx, panel-local rows)
    int loffA[4], loffB[4];
#pragma unroll
    for (int f = 0; f < 4; ++f) {
        const int ra = ((w >> 1) << 6) + (f << 4) + m;
        loffA[f] = (ra << 5) + ((q ^ ((ra >> 1) & 3)) << 3);
        const int rb = ((w & 1) << 6) + (f << 4) + m;
        loffB[f] = (rb << 5) + ((q ^ ((rb >> 1) & 3)) << 3);
    }

    // staging: wave w copies ushorts [w*1024, (w+1)*1024) of each 8KB panel,
    // two glds issues each (lane offset = lane*16B, HW-linear).
    const int sg = (w << 10) + (l << 3);
    const ushort* gA0 = Zc + (size_t)I0 * 32 + sg;
    const ushort* gB0 = Zc + (size_t)J0 * 32 + sg;
    const int lo = w << 10;

    // prologue: stage ck0 -> buf0 (oldest 4), ck1 -> buf1; wait ck0 only.
    GLDS16(gA0,        &bufA[0][lo]);
    GLDS16(gA0 + 512,  &bufA[0][lo + 512]);
    GLDS16(gB0,        &bufB[0][lo]);
    GLDS16(gB0 + 512,  &bufB[0][lo + 512]);
    GLDS16(gA0 + CKS,       &bufA[1][lo]);
    GLDS16(gA0 + CKS + 512, &bufA[1][lo + 512]);
    GLDS16(gB0 + CKS,       &bufB[1][lo]);
    GLDS16(gB0 + CKS + 512, &bufB[1][lo + 512]);
    WAITVM4;
    __builtin_amdgcn_s_barrier();
    __builtin_amdgcn_sched_barrier(0);

    floatx4 accf[4][4];
#pragma unroll
    for (int fi = 0; fi < 4; ++fi)
#pragma unroll
        for (int fj = 0; fj < 4; ++fj) accf[fi][fj] = (floatx4){0.f, 0.f, 0.f, 0.f};

    // ---- main K loop: 8 chunks, depth-2 glds, counted vmcnt, raw barrier ----
#pragma unroll
    for (int ck = 0; ck < 8; ++ck) {
        const ushort* rA = &bufA[ck % 3][0];
        const ushort* rB = &bufB[ck % 3][0];
        short8 fa[4], fb[4];
#pragma unroll
        for (int f = 0; f < 4; ++f) fa[f] = *(const short8*)(rA + loffA[f]);
#pragma unroll
        for (int f = 0; f < 4; ++f) fb[f] = *(const short8*)(rB + loffB[f]);
        if (ck < 6) {
            const size_t ko = (size_t)(ck + 2) * CKS;
            const int nb = (ck + 2) % 3;
            GLDS16(gA0 + ko,       &bufA[nb][lo]);
            GLDS16(gA0 + ko + 512, &bufA[nb][lo + 512]);
            GLDS16(gB0 + ko,       &bufB[nb][lo]);
            GLDS16(gB0 + ko + 512, &bufB[nb][lo + 512]);
        }
#pragma unroll
        for (int fi = 0; fi < 4; ++fi)
#pragma unroll
            for (int fj = 0; fj < 4; ++fj)
                accf[fi][fj] = __builtin_amdgcn_mfma_f32_16x16x32_bf16(fa[fi], fb[fj], accf[fi][fj], 0, 0, 0);
        if (ck < 7) {
            if (ck < 6) { WAITVM4; } else { WAITVM0; }   // ck=6: ck7 issued 1 iter ago
            __builtin_amdgcn_s_barrier();
            __builtin_amdgcn_sched_barrier(0);
        }
    }

    // ---- epilogue (no barriers until final reduce) ----
    float lsum = 0.f;
    if (active) {
        float c2[NSIG];
#pragma unroll
        for (int k = 0; k < NSIG; ++k) c2[k] = (-0.5f / sigmas[k]) * 1.44269504f;

        const float sgn2 = ((i0 < 4096) == (j0 < 4096)) ? 2.f : -2.f;

        float njs[4];
#pragma unroll
        for (int fj = 0; fj < 4; ++fj) njs[fj] = norms[j0 + (fj << 4) + m];

#pragma unroll
        for (int fi = 0; fi < 4; ++fi) {
            const floatx4 ni4 = *(const floatx4*)(norms + i0 + (fi << 4) + (q << 2));
#pragma unroll
            for (int fj = 0; fj < 4; ++fj) {
#pragma unroll
                for (int v = 0; v < 4; ++v) {
                    float d = fmaf(-2.f, accf[fi][fj][v], ni4[v] + njs[fj]);
                    d = fmaxf(d, 0.f);
                    if (diag) {
                        const int dif = ((fi - fj) << 4) + ((q << 2) + v) - m;   // gi - gj
                        d = (dif < 0) ? d : 3.0e9f;    // strictly-upper only
                    }
                    accf[fi][fj][v] = d;
                }
            }
        }

        float dmin = accf[0][0][0];
#pragma unroll
        for (int fi = 0; fi < 4; ++fi)
#pragma unroll
            for (int fj = 0; fj < 4; ++fj)
#pragma unroll
                for (int v = 0; v < 4; ++v) dmin = fminf(dmin, accf[fi][fj][v]);
#pragma unroll
        for (int off = 1; off < 64; off <<= 1) dmin = fminf(dmin, __shfl_xor(dmin, off, 64));

        float tsum = 0.f;
#pragma unroll
        for (int k = 0; k < NSIG; ++k) {
            if (c2[k] * dmin >= -126.f) {   // wave-uniform skip iff all exps underflow
#pragma unroll
                for (int fi = 0; fi < 4; ++fi)
#pragma unroll
                    for (int fj = 0; fj < 4; ++fj)
#pragma unroll
                        for (int v = 0; v < 4; ++v)
                            tsum += __builtin_amdgcn_exp2f(c2[k] * accf[fi][fj][v]);
            }
        }
        lsum = sgn2 * tsum;
    }

    // ---- block reduce + store ----
#pragma unroll
    for (int off = 32; off > 0; off >>= 1) lsum += __shfl_down(lsum, off, 64);
    if (l == 0) wsum[w] = lsum;
    __syncthreads();
    if (t == 0) partials[blockIdx.x] = wsum[0] + wsum[1] + wsum[2] + wsum[3];
}

__global__ __launch_bounds__(256) void finalize_kernel(const float* __restrict__ partials,
                                                       float* __restrict__ out) {
    __shared__ double sh[256];
    const int t = threadIdx.x;
    double s = 0.0;
    for (int i = t; i < NBLK2; i += 256) s += (double)partials[i];
    sh[t] = s;
    __syncthreads();
    for (int st = 128; st > 0; st >>= 1) {
        if (t < st) sh[t] += sh[t + st];
        __syncthreads();
    }
    if (t == 0) out[0] = (float)((sh[0] + 8192.0 * NSIG) * (1.0 / (4096.0 * 4096.0)));
}

extern "C" void kernel_launch(void* const* d_in, const int* in_sizes, int n_in,
                              void* d_out, int out_size, void* d_ws, size_t ws_size,
                              hipStream_t stream) {
    const float* x   = (const float*)d_in[0];
    const float* y   = (const float*)d_in[1];
    const float* sig = (const float*)d_in[2];

    ushort* Zc      = (ushort*)d_ws;                                   // 4 MiB
    float* norms    = (float*)((char*)d_ws + (size_t)8192 * 256 * 2);  // 32 KiB
    float* partials = (float*)((char*)norms + 8192 * sizeof(float));   // 2080 floats
    float* out      = (float*)d_out;

    prep_kernel<<<512, 256, 0, stream>>>(x, y, Zc, norms);
    gemm_epi<<<NBLK2, 256, 0, stream>>>(Zc, norms, sig, partials);
    finalize_kernel<<<1, 256, 0, stream>>>(partials, out);
}